// Round 8
// baseline (228.617 us; speedup 1.0000x reference)
//
#include <hip/hip_runtime.h>

// SparseAttention: B=8, M=N=4096, K=64, R=128 nnz/row (uniform CSR, sorted cols).
// R2-R8 established: the gather structure is capped by per-CU outstanding-line
// limit (~0.26 lines/cy/CU, time proportional to random 128-B line count,
// invariant to MLP depth once >5 — R8's hw-pinned 16-deep clause proved it).
// R9: LDS column-sweep (flash-style). Block = 128 rows x 1 batch; sweep 16
//     column-tiles of 256; stream dense K/V tile into LDS (double-buffered,
//     reg-staged, 144-B padded stride vs bank conflicts); serve the random
//     per-edge reads from LDS (~85 B/cy/CU) instead of L2 (MSHR-capped).
//     Sorted cols -> ballot-based 8-wide pointer walk; exact online softmax.
#define Bc 8
#define Mc 4096
#define Nc 4096
#define Kc 64
#define Rc 128
#define Tc 256          // columns per LDS tile
#define NT (Nc / Tc)    // 16 tiles
#define KST 144         // padded bytes per K/V row in LDS (128 + 16, keeps 16-B align)

typedef _Float16 h16;
typedef h16 h16x2 __attribute__((ext_vector_type(2)));
typedef h16 h16x4 __attribute__((ext_vector_type(4)));
typedef h16 h16x8 __attribute__((ext_vector_type(8)));
typedef float f32x4 __attribute__((ext_vector_type(4)));

// DPP cross-lane reduce (validated in R7/R8): xor1=0xB1, xor2=0x4E,
// row_half_mirror=0x141 (==xor4 once quads uniform) -> 8-lane group sum.
template<int CTRL>
__device__ __forceinline__ float dpp_badd(float x) {
    union { float f; int i; } u, r;
    u.f = x;
    r.i = __builtin_amdgcn_update_dpp(0, u.i, CTRL, 0xF, 0xF, true);
    return x + r.f;
}

// fp32 -> fp16 staging for K, V, Q.  XCD-aware: batch b converted by blocks
// with blockIdx&7 == b (same XCD the sweep blocks for batch b run on).
__global__ __launch_bounds__(256) void cvt_fp16(
    const f32x4* __restrict__ K4, const f32x4* __restrict__ V4,
    const f32x4* __restrict__ Q4,
    h16x4* __restrict__ Kh4, h16x4* __restrict__ Vh4, h16x4* __restrict__ Qh4)
{
    const int nb4   = Nc * Kc / 4;          // 65536 f32x4 per tensor per batch
    const int b     = blockIdx.x & 7;       // XCD == batch
    const int chunk = blockIdx.x >> 3;      // 0..767
    const int tsel  = chunk >> 8;           // 0:K 1:V 2:Q (256 blocks each)
    const int idx   = b * nb4 + ((chunk & 255) << 8) + threadIdx.x;
    const f32x4* src = (tsel == 0) ? K4 : (tsel == 1) ? V4 : Q4;
    h16x4*       dst = (tsel == 0) ? Kh4 : (tsel == 1) ? Vh4 : Qh4;
    f32x4 v = __builtin_nontemporal_load(&src[idx]);
    h16x4 o = { (h16)v.x, (h16)v.y, (h16)v.z, (h16)v.w };
    dst[idx] = o;
}

__global__ __launch_bounds__(512, 2) void sattn_sweep(
    const int* __restrict__ cols,    // [M*R], sorted within row
    const h16* __restrict__ Qh,      // [B,M,K] fp16 (staged)
    const h16* __restrict__ Kh,      // [B,N,K] fp16 (staged)
    const h16* __restrict__ Vh,      // [B,N,K] fp16 (staged)
    float* __restrict__ out)         // [B,M,K] fp32
{
    const int b     = blockIdx.x & 7;        // XCD swizzle: one batch per XCD
    const int rblk  = blockIdx.x >> 3;       // 0..31 row-block within batch
    const int tid   = threadIdx.x;           // 0..511 (8 waves)
    const int l     = tid & 63;
    const int ln    = tid & 7;               // lane in 8-lane group; dims ln*8..+7
    const int gbase = l & 56;                // group base lane within wave
    const int gg    = tid >> 3;              // group 0..63; owns rows r0,r1
    const int r0    = rblk * 128 + gg * 2;
    const int r1    = r0 + 1;

    // [buf][K=0/V=1][Tc rows of 144 B]  = 147456 B
    __shared__ __align__(16) char smem[2][2][Tc * KST];

    const h16* Kb = Kh + ((size_t)b * Nc) * Kc;
    const h16* Vb = Vh + ((size_t)b * Nc) * Kc;

    // Q fragments for both rows (16 B each; 8 lanes of group share the row).
    h16x8 q0 = *(const h16x8*)(Qh + (((size_t)b * Mc + r0) << 6) + ln * 8);
    h16x8 q1 = *(const h16x8*)(Qh + (((size_t)b * Mc + r1) << 6) + ln * 8);

    const int* crow0 = cols + r0 * Rc;
    const int* crow1 = cols + r1 * Rc;

    int   ptr0 = 0, ptr1 = 0;
    float m0 = -1e30f, s0 = 0.f;
    float m1 = -1e30f, s1 = 0.f;
    float acc0[8] = {0.f,0.f,0.f,0.f,0.f,0.f,0.f,0.f};
    float acc1[8] = {0.f,0.f,0.f,0.f,0.f,0.f,0.f,0.f};

    // staging geometry: thread -> 4 contiguous 16-B pieces per tensor.
    // piece (scol, schb+i): src = base + scol*64 + (schb+i)*8 (h16 units),
    // dst = scol*KST + (schb+i)*16 (padded).
    const int scol = tid >> 1;               // 0..255
    const int schb = (tid & 1) * 4;          // 0 or 4

    // ---- prologue: stage tile 0 into buf 0 ----
    {
        #pragma unroll
        for (int i = 0; i < 4; ++i) {
            h16x8 a = *(const h16x8*)(Kb + (size_t)scol * 64 + (schb + i) * 8);
            h16x8 c = *(const h16x8*)(Vb + (size_t)scol * 64 + (schb + i) * 8);
            *(h16x8*)(&smem[0][0][scol * KST + (schb + i) * 16]) = a;
            *(h16x8*)(&smem[0][1][scol * KST + (schb + i) * 16]) = c;
        }
    }
    __syncthreads();

    for (int t = 0; t < NT; ++t) {
        const int cur   = t & 1;
        const int c0    = t * Tc;
        const int c_end = c0 + Tc;

        // prefetch next tile into registers (streams; latency hides under compute)
        h16x8 sk[4], sv[4];
        if (t + 1 < NT) {
            const h16* sK = Kb + (size_t)(t + 1) * Tc * 64;
            const h16* sV = Vb + (size_t)(t + 1) * Tc * 64;
            #pragma unroll
            for (int i = 0; i < 4; ++i) {
                sk[i] = *(const h16x8*)(sK + (size_t)scol * 64 + (schb + i) * 8);
                sv[i] = *(const h16x8*)(sV + (size_t)scol * 64 + (schb + i) * 8);
            }
        }

        const char* ldK = smem[cur][0];
        const char* ldV = smem[cur][1];

        // process one row's edges that fall inside [c0, c_end)
        auto process = [&](const int* crow, int& ptr, float& m, float& s,
                           float* acc, h16x8 q) {
            for (;;) {
                int idx  = ptr + ln;
                int cidx = idx < Rc ? idx : Rc - 1;
                int cv   = crow[cidx];
                bool valid = (idx < Rc) && (cv < c_end);
                unsigned long long bal = __ballot(valid);
                int n = __popcll((bal >> gbase) & 0xFFull);   // group-uniform
                if (n > 0) {
                    int cc[8]; h16x8 kf[8]; float lg[8];
                    #pragma unroll
                    for (int j = 0; j < 8; ++j) if (j < n) {
                        cc[j] = __shfl(cv, gbase + j, 64) - c0;
                        kf[j] = *(const h16x8*)(ldK + cc[j] * KST + ln * 16);
                    }
                    #pragma unroll
                    for (int j = 0; j < 8; ++j) if (j < n) {
                        float a = 0.f;
                        #pragma unroll
                        for (int d = 0; d < 4; ++d) {
                            h16x2 qj = { q[2*d], q[2*d+1] };
                            h16x2 kj = { kf[j][2*d], kf[j][2*d+1] };
#if defined(__has_builtin)
#if __has_builtin(__builtin_amdgcn_fdot2)
                            a = __builtin_amdgcn_fdot2(qj, kj, a, false);
#else
                            a += (float)qj.x*(float)kj.x + (float)qj.y*(float)kj.y;
#endif
#else
                            a += (float)qj.x*(float)kj.x + (float)qj.y*(float)kj.y;
#endif
                        }
                        a = dpp_badd<0xB1>(a);
                        a = dpp_badd<0x4E>(a);
                        a = dpp_badd<0x141>(a);
                        lg[j] = a;                       // group-uniform logit
                    }
                    // online softmax: one rescale per chunk
                    float cm = -1e30f;
                    #pragma unroll
                    for (int j = 0; j < 8; ++j) if (j < n) cm = fmaxf(cm, lg[j]);
                    if (cm > m) {
                        float sc = __expf(m - cm);
                        s *= sc;
                        #pragma unroll
                        for (int d = 0; d < 8; ++d) acc[d] *= sc;
                        m = cm;
                    }
                    #pragma unroll
                    for (int j = 0; j < 8; ++j) if (j < n) {
                        lg[j] = __expf(lg[j] - m);
                        s += lg[j];
                    }
                    h16x8 vf[8];
                    #pragma unroll
                    for (int j = 0; j < 8; ++j) if (j < n)
                        vf[j] = *(const h16x8*)(ldV + cc[j] * KST + ln * 16);
                    #pragma unroll
                    for (int j = 0; j < 8; ++j) if (j < n) {
                        #pragma unroll
                        for (int d = 0; d < 8; ++d)
                            acc[d] = fmaf((float)vf[j][d], lg[j], acc[d]);
                    }
                    ptr += n;
                }
                if (n < 8) break;   // fewer than 8 valid -> tile exhausted
            }
        };
        process(crow0, ptr0, m0, s0, acc0, q0);
        process(crow1, ptr1, m1, s1, acc1, q1);

        // publish prefetched tile into the other buffer (disjoint from cur;
        // previous reads of it ended before the previous barrier)
        if (t + 1 < NT) {
            const int nxt = cur ^ 1;
            #pragma unroll
            for (int i = 0; i < 4; ++i) {
                *(h16x8*)(&smem[nxt][0][scol * KST + (schb + i) * 16]) = sk[i];
                *(h16x8*)(&smem[nxt][1][scol * KST + (schb + i) * 16]) = sv[i];
            }
        }
        __syncthreads();
    }

    // ---- epilogue: normalize and write both rows ----
    {
        float inv = 1.0f / s0;
        float* o = out + (((size_t)b * Mc + r0) << 6) + ln * 8;
        f32x4 x = { acc0[0]*inv, acc0[1]*inv, acc0[2]*inv, acc0[3]*inv };
        f32x4 y = { acc0[4]*inv, acc0[5]*inv, acc0[6]*inv, acc0[7]*inv };
        *(f32x4*)o = x; *((f32x4*)o + 1) = y;
    }
    {
        float inv = 1.0f / s1;
        float* o = out + (((size_t)b * Mc + r1) << 6) + ln * 8;
        f32x4 x = { acc1[0]*inv, acc1[1]*inv, acc1[2]*inv, acc1[3]*inv };
        f32x4 y = { acc1[4]*inv, acc1[5]*inv, acc1[6]*inv, acc1[7]*inv };
        *(f32x4*)o = x; *((f32x4*)o + 1) = y;
    }
}

extern "C" void kernel_launch(void* const* d_in, const int* in_sizes, int n_in,
                              void* d_out, int out_size, void* d_ws, size_t ws_size,
                              hipStream_t stream) {
    // inputs: 0 row_indices, 1 row_offsets, 2 column_indices, 3 q3d, 4 k3d, 5 v3d, 6 values
    const int*   cols = (const int*)d_in[2];
    const float* Qm   = (const float*)d_in[3];
    const float* Km   = (const float*)d_in[4];
    const float* Vm   = (const float*)d_in[5];
    float* out = (float*)d_out;

    h16* Kh = (h16*)d_ws;
    h16* Vh = Kh + (size_t)Bc * Nc * Kc;
    h16* Qh = Vh + (size_t)Bc * Nc * Kc;   // 3 x 4.19 MB = 12.6 MB in d_ws

    cvt_fp16<<<dim3(Bc * 3 * 256), dim3(256), 0, stream>>>(
        (const f32x4*)Km, (const f32x4*)Vm, (const f32x4*)Qm,
        (h16x4*)Kh, (h16x4*)Vh, (h16x4*)Qh);

    // 256 blocks = 8 batches x 32 row-blocks; 1 block/CU (144 KB LDS).
    sattn_sweep<<<dim3(Bc * Mc / 128), dim3(512), 0, stream>>>(
        cols, Qh, Kh, Vh, out);
}

// Round 9
// 140.435 us; speedup vs baseline: 1.6279x; 1.6279x over previous
//
#include <hip/hip_runtime.h>

// SparseAttention: B=8, M=N=4096, K=64, R=128 nnz/row (uniform CSR).
// Model: random-gather line-rate bound at 0.258 lines/cy/CU (= ~1 fill / 4cy:
// smells like L1/TCP fill rate, hypothesis H3).  R8's deep-clause probe never
// ran (stale binary: VGPR=40 identical to R7 — impossible with 16 live b128).
// R10: R8's inline-asm 16-deep gather clause (volatile, order-pinned,
//      s_waitcnt vmcnt(8)/vmcnt(0) + sched_barrier(0), "=&v" early-clobber)
//      PLUS "sc0 nt" on the gathers -> bypass L1 allocation (agent scope).
// Diagnostic gate: VGPR_Count must rise to ~100+.  H3/H1 -> 32-42us.
// H2 (L2-side cap) -> flat ~53us with clause verified -> gather roofline.
#define Bc 8
#define Mc 4096
#define Nc 4096
#define Kc 64
#define Rc 128

typedef _Float16 h16;
typedef h16 h16x2 __attribute__((ext_vector_type(2)));
typedef h16 h16x4 __attribute__((ext_vector_type(4)));
typedef h16 h16x8 __attribute__((ext_vector_type(8)));
typedef float f32x4 __attribute__((ext_vector_type(4)));
typedef int   i32x4 __attribute__((ext_vector_type(4)));

// DPP cross-lane reduce helpers (VALU, no DS pipe).
// XOR1 = quad_perm[1,0,3,2]=0xB1, XOR2 = quad_perm[2,3,0,1]=0x4E,
// MIR  = row_half_mirror=0x141 (== xor4 once each quad is uniform),
// ROR8 = row_ror:8=0x128 (exact xor8 within a 16-lane row).
template<int CTRL>
__device__ __forceinline__ float dpp_badd(float x) {
    union { float f; int i; } u, r;
    u.f = x;
    r.i = __builtin_amdgcn_update_dpp(0, u.i, CTRL, 0xF, 0xF, true);
    return x + r.f;
}
template<int CTRL>
__device__ __forceinline__ float dpp_bmax(float x) {
    union { float f; int i; } u, r;
    u.f = x;
    r.i = __builtin_amdgcn_update_dpp(0, u.i, CTRL, 0xF, 0xF, true);
    return fmaxf(x, r.f);
}

// fp32 -> fp16 staging for K, V, Q.  XCD-aware: batch b converted by blocks
// with blockIdx&7 == b (same XCD that sattn's batch-b gathers run on).
__global__ __launch_bounds__(256) void cvt_fp16(
    const f32x4* __restrict__ K4, const f32x4* __restrict__ V4,
    const f32x4* __restrict__ Q4,
    h16x4* __restrict__ Kh4, h16x4* __restrict__ Vh4, h16x4* __restrict__ Qh4)
{
    const int nb4   = Nc * Kc / 4;          // 65536 f32x4 per tensor per batch
    const int b     = blockIdx.x & 7;       // XCD == batch
    const int chunk = blockIdx.x >> 3;      // 0..767
    const int tsel  = chunk >> 8;           // 0:K 1:V 2:Q (256 blocks each)
    const int idx   = b * nb4 + ((chunk & 255) << 8) + threadIdx.x;
    const f32x4* src = (tsel == 0) ? K4 : (tsel == 1) ? V4 : Q4;
    h16x4*       dst = (tsel == 0) ? Kh4 : (tsel == 1) ? Vh4 : Qh4;
    f32x4 v = __builtin_nontemporal_load(&src[idx]);
    h16x4 o = { (h16)v.x, (h16)v.y, (h16)v.z, (h16)v.w };
    dst[idx] = o;
}

__global__ __launch_bounds__(256, 4) void sattn_kernel(
    const int* __restrict__ cols,    // [M*R], sorted within row
    const h16* __restrict__ Qh,      // [B,M,K] fp16 (staged)
    const h16* __restrict__ Kh,      // [B,N,K] fp16 (staged)
    const h16* __restrict__ Vh,      // [B,N,K] fp16 (staged)
    float* __restrict__ out)         // [B,M,K] fp32
{
    const int b    = blockIdx.x & 7;          // XCD swizzle: one batch per XCD L2
    const int rb   = blockIdx.x >> 3;         // row-pair index within batch
    const int w    = threadIdx.x >> 6;        // wave 0..3
    const int rw   = w >> 1;                  // row-in-block 0/1
    const int half = w & 1;                   // which 64 of the row's 128 edges
    const int row  = rb * 2 + rw;
    const int l    = threadIdx.x & 63;
    const int g    = l >> 3;                  // group 0..7
    const int ln   = l & 7;                   // lane-in-group; dims ln*8..ln*8+7

    __shared__ float s_m[2][2];               // per-row per-half max
    __shared__ float s_s[2][2];               // per-row per-half expsum
    __shared__ __align__(16) float s_part[2][64]; // half-1 partial out

    const h16* Kb = Kh + ((size_t)b * Nc) * Kc;
    const h16* Vb = Vh + ((size_t)b * Nc) * Kc;

    // ---- compiler-visible loads FIRST (cols, Q), fully consumed before the
    //      asm clause so hipcc's waitcnt insertion can't touch our stream ----
    const int* crow = cols + row * Rc + half * 64 + g * 8;
    i32x4 c0 = *(const i32x4*)crow;
    i32x4 c1 = *(const i32x4*)(crow + 4);
    int col8[8] = { c0[0], c0[1], c0[2], c0[3], c1[0], c1[1], c1[2], c1[3] };

    h16x8 qv = *(const h16x8*)(Qh + (((size_t)b * Mc + row) << 6) + ln * 8);
    // consume qv into qh NOW (forces the compiler's vmcnt wait here)
    h16x2 qh[4];
    #pragma unroll
    for (int j = 0; j < 4; ++j) qh[j] = h16x2{ qv[2 * j], qv[2 * j + 1] };

    // byte offsets for this group's 8 edges: col*128 + ln*16
    int voff[8];
    #pragma unroll
    for (int p = 0; p < 8; ++p) voff[p] = (col8[p] << 7) + ln * 16;

    // ---- the clause: 16 volatile asm gathers, order-pinned in hardware.
    //      "sc0 nt": agent-scope + non-temporal -> no L1 allocation (H3 probe).
    //      "=&v": dest regs written asynchronously (valid only after waitcnt),
    //      so they must never alias any other operand. ----
    h16x8 kv[8], vv[8];
    #pragma unroll
    for (int p = 0; p < 8; ++p)
        asm volatile("global_load_dwordx4 %0, %1, %2 sc0 nt"
                     : "=&v"(kv[p]) : "v"(voff[p]), "s"(Kb));
    #pragma unroll
    for (int p = 0; p < 8; ++p)
        asm volatile("global_load_dwordx4 %0, %1, %2 sc0 nt"
                     : "=&v"(vv[p]) : "v"(voff[p]), "s"(Vb));
    // K done when only the 8 V loads remain outstanding.
    asm volatile("s_waitcnt vmcnt(8)");
    __builtin_amdgcn_sched_barrier(0);   // rule 18: nothing hoists above this

    // ---- SDDMM dots (fp16 fdot2) + DPP group reduce (xor1,2,4) ----
    float lg[8];
    #pragma unroll
    for (int p = 0; p < 8; ++p) {
        float acc = 0.f;
        #pragma unroll
        for (int j = 0; j < 4; ++j) {
            h16x2 kj = { kv[p][2 * j], kv[p][2 * j + 1] };
#if defined(__has_builtin)
#if __has_builtin(__builtin_amdgcn_fdot2)
            acc = __builtin_amdgcn_fdot2(qh[j], kj, acc, false);
#else
            acc += (float)qh[j].x * (float)kj.x + (float)qh[j].y * (float)kj.y;
#endif
#else
            acc += (float)qh[j].x * (float)kj.x + (float)qh[j].y * (float)kj.y;
#endif
        }
        acc = dpp_badd<0xB1>(acc);    // xor1
        acc = dpp_badd<0x4E>(acc);    // xor2
        acc = dpp_badd<0x141>(acc);   // xor4 (row_half_mirror, quad-uniform)
        lg[p] = acc;                  // logit of edge half*64+g*8+p (all 8 lanes)
    }

    // ---- softmax: local max, cross-wave exchange, exp, sum.
    //      The 8 V loads stay in flight across the barrier (never-drain). ----
    float m = lg[0];
    #pragma unroll
    for (int p = 1; p < 8; ++p) m = fmaxf(m, lg[p]);
    m = dpp_bmax<0x128>(m);                    // xor8 (row_ror:8)
    m = fmaxf(m, __shfl_xor(m, 16, 64));
    m = fmaxf(m, __shfl_xor(m, 32, 64));
    if (l == 0) s_m[rw][half] = m;
    __syncthreads();
    m = fmaxf(s_m[rw][0], s_m[rw][1]);

    float s = 0.f;
    #pragma unroll
    for (int p = 0; p < 8; ++p) { lg[p] = __expf(lg[p] - m); s += lg[p]; }
    s = dpp_badd<0x128>(s);                    // xor8
    s += __shfl_xor(s, 16, 64);
    s += __shfl_xor(s, 32, 64);
    if (l == 0) s_s[rw][half] = s;

    // ---- now (and only now) drain the V stream ----
    asm volatile("s_waitcnt vmcnt(0)");
    __builtin_amdgcn_sched_barrier(0);

    // ---- SPMM over this wave's 64 edges (V in registers) ----
    float acc8[8] = {0.f, 0.f, 0.f, 0.f, 0.f, 0.f, 0.f, 0.f};
    #pragma unroll
    for (int p = 0; p < 8; ++p) {
        const float wp = lg[p];
        #pragma unroll
        for (int j = 0; j < 8; ++j)
            acc8[j] = fmaf((float)vv[p][j], wp, acc8[j]);   // v_fma_mix
    }
    // cross-group reduce: DPP xor8, then shfl 16/32
    #pragma unroll
    for (int j = 0; j < 8; ++j) {
        acc8[j] = dpp_badd<0x128>(acc8[j]);
        acc8[j] += __shfl_xor(acc8[j], 16, 64);
        acc8[j] += __shfl_xor(acc8[j], 32, 64);
    }

    // half-1 publishes its partial (8 lanes x 32B, conflict-free)
    if (half == 1 && g == 0) {
        *(f32x4*)&s_part[rw][ln * 8]     = f32x4{acc8[0], acc8[1], acc8[2], acc8[3]};
        *(f32x4*)&s_part[rw][ln * 8 + 4] = f32x4{acc8[4], acc8[5], acc8[6], acc8[7]};
    }
    __syncthreads();

    if (half == 0 && g == 0) {
        const float inv = 1.0f / (s_s[rw][0] + s_s[rw][1]);
        const float* pp = &s_part[rw][ln * 8];
        float* orow = out + (((size_t)b * Mc + row) << 6) + ln * 8;
        f32x4 o0 = { (acc8[0] + pp[0]) * inv, (acc8[1] + pp[1]) * inv,
                     (acc8[2] + pp[2]) * inv, (acc8[3] + pp[3]) * inv };
        f32x4 o1 = { (acc8[4] + pp[4]) * inv, (acc8[5] + pp[5]) * inv,
                     (acc8[6] + pp[6]) * inv, (acc8[7] + pp[7]) * inv };
        __builtin_nontemporal_store(o0, (f32x4*)orow);
        __builtin_nontemporal_store(o1, (f32x4*)orow + 1);
    }
}

extern "C" void kernel_launch(void* const* d_in, const int* in_sizes, int n_in,
                              void* d_out, int out_size, void* d_ws, size_t ws_size,
                              hipStream_t stream) {
    // inputs: 0 row_indices, 1 row_offsets, 2 column_indices, 3 q3d, 4 k3d, 5 v3d, 6 values
    const int*   cols = (const int*)d_in[2];
    const float* Qm   = (const float*)d_in[3];
    const float* Km   = (const float*)d_in[4];
    const float* Vm   = (const float*)d_in[5];
    float* out = (float*)d_out;

    h16* Kh = (h16*)d_ws;
    h16* Vh = Kh + (size_t)Bc * Nc * Kc;
    h16* Qh = Vh + (size_t)Bc * Nc * Kc;   // 3 x 4.19 MB = 12.6 MB in d_ws

    cvt_fp16<<<dim3(Bc * 3 * 256), dim3(256), 0, stream>>>(
        (const f32x4*)Km, (const f32x4*)Vm, (const f32x4*)Qm,
        (h16x4*)Kh, (h16x4*)Vh, (h16x4*)Qh);

    sattn_kernel<<<dim3(Bc * Mc / 2), dim3(256), 0, stream>>>(cols, Qh, Kh, Vh, out);
}